// Round 10
// baseline (329.831 us; speedup 1.0000x reference)
//
#include <hip/hip_runtime.h>
#include <hip/hip_bf16.h>
#include <math.h>

#define DEVI __device__ __forceinline__

typedef __attribute__((ext_vector_type(8))) short bf16x8;
typedef __attribute__((ext_vector_type(4))) float f32x4;

DEVI unsigned short f2bf(float f) {
    union { float f; unsigned u; } v; v.f = f;
    unsigned r = v.u + 0x7FFFu + ((v.u >> 16) & 1u);
    return (unsigned short)(r >> 16);
}

DEVI float bf2f(unsigned short u) {
    union { unsigned u; float f; } v; v.u = (unsigned)u << 16; return v.f;
}

DEVI unsigned cvtpk(float lo, float hi) {   // D = bf16(hi)<<16 | bf16(lo), RNE
    unsigned d;
    asm volatile("v_cvt_pk_bf16_f32 %0, %1, %2" : "=v"(d) : "v"(lo), "v"(hi));
    return d;
}

DEVI void gload16(const void* g, void* l) {
    __builtin_amdgcn_global_load_lds((const __attribute__((address_space(1))) void*)g,
                                     (__attribute__((address_space(3))) void*)l, 16, 0, 0);
}

#define WAITVM8() asm volatile("s_waitcnt vmcnt(8)" ::: "memory")
#define WAITVM4() asm volatile("s_waitcnt vmcnt(4)" ::: "memory")
#define WAITVM0() asm volatile("s_waitcnt vmcnt(0)" ::: "memory")
#define WAITLG0() asm volatile("s_waitcnt lgkmcnt(0)" ::: "memory")
#define BAR()     __builtin_amdgcn_s_barrier()

// ---------------- fused pre-pass: 6 weight fake-quants + LN1, one dispatch ----------------
__global__ __launch_bounds__(256) void fused_pre_kernel(
    const float* __restrict__ Wq, const float* __restrict__ Wk, const float* __restrict__ Wv,
    const float* __restrict__ Wp, const float* __restrict__ W1, const float* __restrict__ W2,
    const float* __restrict__ eq, const float* __restrict__ ek, const float* __restrict__ ev,
    const float* __restrict__ ep, const float* __restrict__ e1, const float* __restrict__ e2,
    const float* __restrict__ bq, const float* __restrict__ bk, const float* __restrict__ bv,
    const float* __restrict__ bp, const float* __restrict__ b1, const float* __restrict__ b2,
    unsigned short* __restrict__ Wqkvq, unsigned short* __restrict__ Wpq,
    unsigned short* __restrict__ W1q, unsigned short* __restrict__ W2q,
    const float* __restrict__ x, const float* __restrict__ g1, const float* __restrict__ be1,
    unsigned short* __restrict__ hbuf)
{
    const int M1 = 1 << 20;
    if (blockIdx.x < 2048) {
        const int NCH = 3 * M1;
        const int STRIDE = 2048 * 256;
        for (int c = blockIdx.x * blockDim.x + threadIdx.x; c < NCH; c += STRIDE) {
            int elem = c * 4;
            const float *W, *e, *b; unsigned short* o; int lgK, local;
            if (elem < M1)            { W = Wq; e = eq; b = bq; o = Wqkvq;          lgK = 10; local = elem; }
            else if (elem < 2 * M1)   { W = Wk; e = ek; b = bk; o = Wqkvq + M1;     lgK = 10; local = elem - M1; }
            else if (elem < 3 * M1)   { W = Wv; e = ev; b = bv; o = Wqkvq + 2 * M1; lgK = 10; local = elem - 2 * M1; }
            else if (elem < 4 * M1)   { W = Wp; e = ep; b = bp; o = Wpq;            lgK = 10; local = elem - 3 * M1; }
            else if (elem < 8 * M1)   { W = W1; e = e1; b = b1; o = W1q;            lgK = 10; local = elem - 4 * M1; }
            else                      { W = W2; e = e2; b = b2; o = W2q;            lgK = 12; local = elem - 8 * M1; }
            int row = local >> lgK;
            float evv = e[row], bvv = b[row];
            float br = fmaxf(bvv, 0.f);
            float mn, mx;
            if (br > 0.f) { float p = exp2f(br - 1.f); mn = -p; mx = p - 1.f; }
            else          { mn = 0.f; mx = 0.f; }
            float si = exp2f(-evv), so = exp2f(evv);
            union { float4 v4; float a[4]; } v;
            v.v4 = *(const float4*)(W + local);
            union { unsigned short u[4]; unsigned long long ll; } ot;
            #pragma unroll
            for (int j = 0; j < 4; j++) {
                float qw = fminf(fmaxf(si * v.a[j], mn), mx);
                ot.u[j] = f2bf(so * rintf(qw));
            }
            *(unsigned long long*)(o + local) = ot.ll;
        }
    } else {
        int row = (blockIdx.x - 2048) * 4 + (threadIdx.x >> 6);
        int lane = threadIdx.x & 63;
        const float* xp = x + (size_t)row * 1024 + lane * 16;
        float a[16];
        #pragma unroll
        for (int j = 0; j < 4; j++) {
            float4 v = *(const float4*)(xp + j * 4);
            a[j * 4] = v.x; a[j * 4 + 1] = v.y; a[j * 4 + 2] = v.z; a[j * 4 + 3] = v.w;
        }
        float s = 0.f, s2 = 0.f;
        #pragma unroll
        for (int i = 0; i < 16; i++) { s += a[i]; s2 += a[i] * a[i]; }
        #pragma unroll
        for (int off = 1; off < 64; off <<= 1) { s += __shfl_xor(s, off); s2 += __shfl_xor(s2, off); }
        float mu = s * (1.0f / 1024.0f);
        float var = s2 * (1.0f / 1024.0f) - mu * mu;
        float rs = rsqrtf(var + 1e-5f);
        int c0 = lane * 16;
        float r[16];
        #pragma unroll
        for (int i = 0; i < 16; i++) r[i] = (a[i] - mu) * rs * g1[c0 + i] + be1[c0 + i];
        unsigned w[8];
        #pragma unroll
        for (int j = 0; j < 8; j++) w[j] = cvtpk(r[2 * j], r[2 * j + 1]);
        unsigned short* op = hbuf + (size_t)row * 1024 + c0;
        *(uint4*)(op)     = *(uint4*)&w[0];
        *(uint4*)(op + 8) = *(uint4*)&w[4];
    }
}

// ---------------- LayerNorm wave-per-row, bf16 in -> bf16 out (LN2) ----------------
__global__ __launch_bounds__(256) void ln_bf_kernel(
    const unsigned short* __restrict__ xb, const float* __restrict__ g, const float* __restrict__ be,
    unsigned short* __restrict__ out)
{
    int row = blockIdx.x * 4 + (threadIdx.x >> 6);
    int lane = threadIdx.x & 63;
    const unsigned short* xp = xb + (size_t)row * 1024 + lane * 16;
    float a[16];
    #pragma unroll
    for (int j = 0; j < 2; j++) {
        bf16x8 v = *(const bf16x8*)(xp + j * 8);
        #pragma unroll
        for (int i = 0; i < 8; i++) a[j * 8 + i] = bf2f(((unsigned short*)&v)[i]);
    }
    float s = 0.f, s2 = 0.f;
    #pragma unroll
    for (int i = 0; i < 16; i++) { s += a[i]; s2 += a[i] * a[i]; }
    #pragma unroll
    for (int off = 1; off < 64; off <<= 1) { s += __shfl_xor(s, off); s2 += __shfl_xor(s2, off); }
    float mu = s * (1.0f / 1024.0f);
    float var = s2 * (1.0f / 1024.0f) - mu * mu;
    float rs = rsqrtf(var + 1e-5f);
    int c0 = lane * 16;
    float r[16];
    #pragma unroll
    for (int i = 0; i < 16; i++) r[i] = (a[i] - mu) * rs * g[c0 + i] + be[c0 + i];
    unsigned w[8];
    #pragma unroll
    for (int j = 0; j < 8; j++) w[j] = cvtpk(r[2 * j], r[2 * j + 1]);
    unsigned short* op = out + (size_t)row * 1024 + c0;
    *(uint4*)(op)     = *(uint4*)&w[0];
    *(uint4*)(op + 8) = *(uint4*)&w[4];
}

// ---------------- GEMM 128x128, BK=64, 8 waves (64x32 wave-tile), counted-vmcnt 2-phase ----
// (r9-proven). EP 0: bf16. EP 2: bf16 relu(acc+bias).
#define GSTAGE8(buf, kt) do { \
    _Pragma("unroll") for (int q_ = 0; q_ < 2; q_++) { \
        int idx_ = q_ * 512 + tid; int row_ = idx_ >> 3; int gs_ = (idx_ & 7) ^ (row_ & 7); \
        gload16(A  + (size_t)(brow + row_) * K + (kt) * 64 + gs_ * 8, &As[buf][idx_ * 8]); \
        gload16(Bw + (size_t)(bcol + row_) * K + (kt) * 64 + gs_ * 8, &Bs[buf][idx_ * 8]); \
    } } while (0)

template<int EP>
__global__ __launch_bounds__(512, 2) void gemm_bt(
    const unsigned short* __restrict__ A, const unsigned short* __restrict__ Bw,
    int N, int K,
    const float* __restrict__ bias, const float* __restrict__ res,
    const unsigned short* __restrict__ resb,
    float* __restrict__ outf, unsigned short* __restrict__ outb)
{
    __shared__ __align__(16) unsigned short As[2][128 * 64];
    __shared__ __align__(16) unsigned short Bs[2][128 * 64];
    int tid = threadIdx.x, lane = tid & 63, wave = tid >> 6;
    int gx = gridDim.x;
    int nwg = gx * gridDim.y;
    int id = blockIdx.y * gx + blockIdx.x;
    int swz = (id & 7) * (nwg >> 3) + (id >> 3);
    int brow = (swz / gx) * 128, bcol = (swz % gx) * 128;
    int wr = wave >> 2, wc = wave & 3;       // 2 M-waves x 4 N-waves; wave tile 64x32
    int r = lane & 15, g4 = lane >> 4;
    f32x4 acc[4][2];
    #pragma unroll
    for (int i = 0; i < 4; i++)
        #pragma unroll
        for (int j = 0; j < 2; j++) acc[i][j] = (f32x4){0.f, 0.f, 0.f, 0.f};

    int nt = K >> 6;
    GSTAGE8(0, 0);
    __syncthreads();
    int cur = 0;
    for (int t = 0; t < nt; ++t) {
        if (t + 1 < nt) { GSTAGE8(cur ^ 1, t + 1); WAITVM4(); }
        else            { WAITVM0(); }
        __builtin_amdgcn_s_barrier();
        #pragma unroll
        for (int kk = 0; kk < 2; kk++) {
            bf16x8 af[4], bfr[2];
            #pragma unroll
            for (int mi = 0; mi < 4; mi++) {
                int rh = wr * 64 + mi * 16 + r;
                af[mi] = *(const bf16x8*)&As[cur][rh * 64 + (((kk * 4 + g4) ^ (rh & 7)) << 3)];
            }
            #pragma unroll
            for (int ni = 0; ni < 2; ni++) {
                int rh = wc * 32 + ni * 16 + r;
                bfr[ni] = *(const bf16x8*)&Bs[cur][rh * 64 + (((kk * 4 + g4) ^ (rh & 7)) << 3)];
            }
            #pragma unroll
            for (int mi = 0; mi < 4; mi++)
                #pragma unroll
                for (int ni = 0; ni < 2; ni++)
                    acc[mi][ni] = __builtin_amdgcn_mfma_f32_16x16x32_bf16(af[mi], bfr[ni], acc[mi][ni], 0, 0, 0);
        }
        __builtin_amdgcn_s_barrier();
        cur ^= 1;
    }

    #pragma unroll
    for (int mi = 0; mi < 4; mi++)
        #pragma unroll
        for (int ni = 0; ni < 2; ni++)
            #pragma unroll
            for (int i = 0; i < 4; i++) {
                int row = brow + wr * 64 + mi * 16 + g4 * 4 + i;
                int col = bcol + wc * 32 + ni * 16 + r;
                float v = acc[mi][ni][i];
                if (EP == 0) {
                    outb[(size_t)row * N + col] = f2bf(v);
                } else if (EP == 1) {
                    outf[(size_t)row * N + col] = v + bias[col] + res[(size_t)row * N + col];
                } else if (EP == 2) {
                    outb[(size_t)row * N + col] = f2bf(fmaxf(v + bias[col], 0.f));
                } else if (EP == 3) {
                    outb[(size_t)row * N + col] = f2bf(v + bias[col] + res[(size_t)row * N + col]);
                } else {
                    outf[(size_t)row * N + col] = v + bias[col] + bf2f(resb[(size_t)row * N + col]);
                }
            }
}

// ---------------- GEMM 128x128, BK=64, 4 waves (64x64 wave-tile), counted-vmcnt 2-phase ----
// (r8-proven; lower LDS-traffic/FLOP — used for proj and long-K FFN2.)
// EP 3: bf16 = acc+bias+res(f32). EP 4: f32 = acc+bias+resb(bf16).
#define GSTAGE4(buf, kt) do { \
    _Pragma("unroll") for (int q_ = 0; q_ < 4; q_++) { \
        int idx_ = q_ * 256 + tid; int row_ = idx_ >> 3; int gs_ = (idx_ & 7) ^ (row_ & 7); \
        gload16(A  + (size_t)(brow + row_) * K + (kt) * 64 + gs_ * 8, &As[buf][idx_ * 8]); \
        gload16(Bw + (size_t)(bcol + row_) * K + (kt) * 64 + gs_ * 8, &Bs[buf][idx_ * 8]); \
    } } while (0)

template<int EP>
__global__ __launch_bounds__(256) void gemm_bt4(
    const unsigned short* __restrict__ A, const unsigned short* __restrict__ Bw,
    int N, int K,
    const float* __restrict__ bias, const float* __restrict__ res,
    const unsigned short* __restrict__ resb,
    float* __restrict__ outf, unsigned short* __restrict__ outb)
{
    __shared__ __align__(16) unsigned short As[2][128 * 64];
    __shared__ __align__(16) unsigned short Bs[2][128 * 64];
    int tid = threadIdx.x, lane = tid & 63, wave = tid >> 6;
    int gx = gridDim.x;
    int nwg = gx * gridDim.y;
    int id = blockIdx.y * gx + blockIdx.x;
    int swz = (id & 7) * (nwg >> 3) + (id >> 3);
    int brow = (swz / gx) * 128, bcol = (swz % gx) * 128;
    int wr = wave >> 1, wc = wave & 1;
    int r = lane & 15, g4 = lane >> 4;
    f32x4 acc[4][4];
    #pragma unroll
    for (int i = 0; i < 4; i++)
        #pragma unroll
        for (int j = 0; j < 4; j++) acc[i][j] = (f32x4){0.f, 0.f, 0.f, 0.f};

    int nt = K >> 6;
    GSTAGE4(0, 0);
    __syncthreads();
    int cur = 0;
    for (int t = 0; t < nt; ++t) {
        if (t + 1 < nt) { GSTAGE4(cur ^ 1, t + 1); WAITVM8(); }
        else            { WAITVM0(); }
        __builtin_amdgcn_s_barrier();
        #pragma unroll
        for (int kk = 0; kk < 2; kk++) {
            bf16x8 af[4], bfr[4];
            #pragma unroll
            for (int mi = 0; mi < 4; mi++) {
                int rh = wr * 64 + mi * 16 + r;
                af[mi] = *(const bf16x8*)&As[cur][rh * 64 + (((kk * 4 + g4) ^ (rh & 7)) << 3)];
            }
            #pragma unroll
            for (int ni = 0; ni < 4; ni++) {
                int rh = wc * 64 + ni * 16 + r;
                bfr[ni] = *(const bf16x8*)&Bs[cur][rh * 64 + (((kk * 4 + g4) ^ (rh & 7)) << 3)];
            }
            #pragma unroll
            for (int mi = 0; mi < 4; mi++)
                #pragma unroll
                for (int ni = 0; ni < 4; ni++)
                    acc[mi][ni] = __builtin_amdgcn_mfma_f32_16x16x32_bf16(af[mi], bfr[ni], acc[mi][ni], 0, 0, 0);
        }
        __builtin_amdgcn_s_barrier();
        cur ^= 1;
    }

    #pragma unroll
    for (int mi = 0; mi < 4; mi++)
        #pragma unroll
        for (int ni = 0; ni < 4; ni++)
            #pragma unroll
            for (int i = 0; i < 4; i++) {
                int row = brow + wr * 64 + mi * 16 + g4 * 4 + i;
                int col = bcol + wc * 64 + ni * 16 + r;
                float v = acc[mi][ni][i];
                if (EP == 0) {
                    outb[(size_t)row * N + col] = f2bf(v);
                } else if (EP == 1) {
                    outf[(size_t)row * N + col] = v + bias[col] + res[(size_t)row * N + col];
                } else if (EP == 2) {
                    outb[(size_t)row * N + col] = f2bf(fmaxf(v + bias[col], 0.f));
                } else if (EP == 3) {
                    outb[(size_t)row * N + col] = f2bf(v + bias[col] + res[(size_t)row * N + col]);
                } else {
                    outf[(size_t)row * N + col] = v + bias[col] + bf2f(resb[(size_t)row * N + col]);
                }
            }
}

// ---------------- Flash attention: 8 waves, 2 q-tiles share staged K/V ----------------
__global__ __launch_bounds__(512, 4) void attn_kernel(
    const unsigned short* __restrict__ qkv, unsigned short* __restrict__ att)
{
    __shared__ __align__(16) unsigned short Ks[2][64 * 64];
    __shared__ __align__(16) unsigned short Vt[2][64 * 66];
    __shared__ __align__(16) unsigned short Ps[2][64 * 64];
    int tid = threadIdx.x, lane = tid & 63, w = tid >> 6;
    int half = w >> 2;
    int pi = blockIdx.x;                       // 0..3
    int bh = blockIdx.y, bb = bh >> 4, hh = bh & 15;
    int r = lane & 15, g4 = lane >> 4;
    const unsigned short* base = qkv + (size_t)bb * 1024 * 3072;
    const float SCL = 0.03125f * 1.4426950408889634f;
    int vd = tid & 63, vsb = tid >> 6;
    int prow = (w & 3) * 16 + r;
    int pswz = (r & 7) << 3;

    for (int sidx = 0; sidx < 2; sidx++) {
        int s = sidx ? (7 - pi) : pi;
        int qt = 2 * s + half;
        int qtmax = 2 * s + 1;
        int qrow = qt * 64 + prow;

        bf16x8 qf[2];
        #pragma unroll
        for (int kk = 0; kk < 2; kk++)
            qf[kk] = *(const bf16x8*)&base[(size_t)qrow * 3072 + hh * 64 + kk * 32 + g4 * 8];

        f32x4 oacc[4];
        #pragma unroll
        for (int i = 0; i < 4; i++) oacc[i] = (f32x4){0.f, 0.f, 0.f, 0.f};
        float m_i = -INFINITY, l_i = 0.f;

        unsigned short vtmp[8];
        {
            int row = tid >> 3, slot = tid & 7;
            int gs = slot ^ (row & 7);
            gload16(base + (size_t)row * 3072 + 1024 + hh * 64 + gs * 8, &Ks[0][tid * 8]);
            #pragma unroll
            for (int i2 = 0; i2 < 8; i2++)
                vtmp[i2] = base[(size_t)(vsb * 8 + i2) * 3072 + 2048 + hh * 64 + vd];
            union { unsigned short u[8]; bf16x8 v; } w0;
            #pragma unroll
            for (int i2 = 0; i2 < 8; i2++) w0.u[i2] = vtmp[i2];
            *(bf16x8*)&Vt[0][vd * 66 + (vsb ^ (vd & 7)) * 8] = w0.v;
        }
        __syncthreads();

        for (int ki = 0; ki <= qtmax; ki++) {
            int cur = ki & 1;
            bool pre = (ki < qtmax);
            bool act = (ki <= qt);
            if (pre) {
                int k1 = (ki + 1) * 64;
                int row = tid >> 3, slot = tid & 7;
                int gs = slot ^ (row & 7);
                gload16(base + (size_t)(k1 + row) * 3072 + 1024 + hh * 64 + gs * 8, &Ks[cur ^ 1][tid * 8]);
                #pragma unroll
                for (int i2 = 0; i2 < 8; i2++)
                    vtmp[i2] = base[(size_t)(k1 + vsb * 8 + i2) * 3072 + 2048 + hh * 64 + vd];
            }

            if (act) {
                int k0 = ki * 64;
                f32x4 sacc[4];
                #pragma unroll
                for (int c4 = 0; c4 < 4; c4++) sacc[c4] = (f32x4){0.f, 0.f, 0.f, 0.f};
                #pragma unroll
                for (int c4 = 0; c4 < 4; c4++) {
                    int krow = c4 * 16 + r;
                    #pragma unroll
                    for (int kk = 0; kk < 2; kk++) {
                        int slot = (g4 + kk * 4) ^ (krow & 7);
                        bf16x8 kf = *(const bf16x8*)&Ks[cur][krow * 64 + slot * 8];
                        sacc[c4] = __builtin_amdgcn_mfma_f32_16x16x32_bf16(kf, qf[kk], sacc[c4], 0, 0, 0);
                    }
                }
                bool diag = (ki == qt);
                float sv[4][4];
                float smax = -INFINITY;
                #pragma unroll
                for (int c4 = 0; c4 < 4; c4++)
                    #pragma unroll
                    for (int i = 0; i < 4; i++) {
                        float sa = sacc[c4][i];
                        if (diag && (k0 + c4 * 16 + g4 * 4 + i) > qrow) sa = -INFINITY;
                        sv[c4][i] = sa;
                        smax = fmaxf(smax, sa);
                    }
                smax = fmaxf(smax, __shfl_xor(smax, 16));
                smax = fmaxf(smax, __shfl_xor(smax, 32));
                if (!__all((smax - m_i) * SCL <= 8.f)) {
                    float mn = fmaxf(m_i, smax);
                    float fs = exp2f((m_i - mn) * SCL);
                    m_i = mn;
                    l_i *= fs;
                    #pragma unroll
                    for (int n4 = 0; n4 < 4; n4++)
                        #pragma unroll
                        for (int i = 0; i < 4; i++) oacc[n4][i] *= fs;
                }
                float nb = -m_i * SCL;
                float rsum = 0.f;
                float pv[4][4];
                #pragma unroll
                for (int c4 = 0; c4 < 4; c4++)
                    #pragma unroll
                    for (int i = 0; i < 4; i++) {
                        float p = exp2f(fmaf(sv[c4][i], SCL, nb));
                        pv[c4][i] = p;
                        rsum += p;
                    }
                rsum += __shfl_xor(rsum, 16);
                rsum += __shfl_xor(rsum, 32);
                l_i += rsum;
                #pragma unroll
                for (int c4 = 0; c4 < 4; c4++) {
                    unsigned long long ll = (unsigned long long)cvtpk(pv[c4][0], pv[c4][1])
                                          | ((unsigned long long)cvtpk(pv[c4][2], pv[c4][3]) << 32);
                    *(unsigned long long*)&Ps[half][(prow * 64 + c4 * 16 + g4 * 4) ^ pswz] = ll;
                }
                WAITLG0();
            }
            if (pre) {
                union { unsigned short u[8]; bf16x8 v; } w0;
                #pragma unroll
                for (int i2 = 0; i2 < 8; i2++) w0.u[i2] = vtmp[i2];
                *(bf16x8*)&Vt[cur ^ 1][vd * 66 + (vsb ^ (vd & 7)) * 8] = w0.v;
            }
            if (act) {
                bf16x8 pa[2];
                #pragma unroll
                for (int kk = 0; kk < 2; kk++)
                    pa[kk] = *(const bf16x8*)&Ps[half][(prow * 64 + kk * 32 + g4 * 8) ^ pswz];
                #pragma unroll
                for (int n4 = 0; n4 < 4; n4++) {
                    int d = n4 * 16 + r;
                    #pragma unroll
                    for (int kk = 0; kk < 2; kk++) {
                        bf16x8 vf = *(const bf16x8*)&Vt[cur][d * 66 + (((kk * 4 + g4) ^ (d & 7)) << 3)];
                        oacc[n4] = __builtin_amdgcn_mfma_f32_16x16x32_bf16(vf, pa[kk], oacc[n4], 0, 0, 0);
                    }
                }
            }
            __syncthreads();
        }

        float inv = 1.f / l_i;
        #pragma unroll
        for (int n4 = 0; n4 < 4; n4++) {
            unsigned long long ll = (unsigned long long)cvtpk(oacc[n4][0] * inv, oacc[n4][1] * inv)
                                  | ((unsigned long long)cvtpk(oacc[n4][2] * inv, oacc[n4][3] * inv) << 32);
            size_t oidx = ((size_t)(bb * 1024 + qrow)) * 1024 + hh * 64 + n4 * 16 + g4 * 4;
            *(unsigned long long*)&att[oidx] = ll;
        }
    }
}

// ---------------- host ----------------
extern "C" void kernel_launch(void* const* d_in, const int* in_sizes, int n_in,
                              void* d_out, int out_size, void* d_ws, size_t ws_size,
                              hipStream_t stream)
{
    const float* x     = (const float*)d_in[0];
    const float* Wq    = (const float*)d_in[1];
    const float* Wk    = (const float*)d_in[2];
    const float* Wv    = (const float*)d_in[3];
    const float* eq    = (const float*)d_in[4];
    const float* bq    = (const float*)d_in[5];
    const float* ek    = (const float*)d_in[6];
    const float* bk    = (const float*)d_in[7];
    const float* ev    = (const float*)d_in[8];
    const float* bv    = (const float*)d_in[9];
    const float* Wp    = (const float*)d_in[10];
    const float* ep    = (const float*)d_in[11];
    const float* bp    = (const float*)d_in[12];
    const float* biasp = (const float*)d_in[13];
    const float* W1    = (const float*)d_in[14];
    const float* e1    = (const float*)d_in[15];
    const float* b1    = (const float*)d_in[16];
    const float* bias1 = (const float*)d_in[17];
    const float* W2    = (const float*)d_in[18];
    const float* e2    = (const float*)d_in[19];
    const float* b2    = (const float*)d_in[20];
    const float* bias2 = (const float*)d_in[21];
    const float* g1    = (const float*)d_in[22];
    const float* be1   = (const float*)d_in[23];
    const float* g2    = (const float*)d_in[24];
    const float* be2   = (const float*)d_in[25];

    const size_t MB = 1ull << 20;
    char* ws = (char*)d_ws;
    unsigned short* Wqkvq = (unsigned short*)(ws);            //  6 MB
    unsigned short* Wpq   = (unsigned short*)(ws + 6 * MB);   //  2 MB
    unsigned short* W1q   = (unsigned short*)(ws + 8 * MB);   //  8 MB
    unsigned short* W2q   = (unsigned short*)(ws + 16 * MB);  //  8 MB
    unsigned short* hbuf  = (unsigned short*)(ws + 24 * MB);  // 16 MB
    unsigned short* qkvb  = (unsigned short*)(ws + 40 * MB);  // 48 MB; later f (64 MB)
    unsigned short* fbuf  = qkvb;
    unsigned short* attb  = (unsigned short*)(ws + 88 * MB);  // 16 MB
    unsigned short* x2b   = (unsigned short*)(ws + 104 * MB); // 16 MB (bf16 residual)

    fused_pre_kernel<<<4096, 256, 0, stream>>>(Wq, Wk, Wv, Wp, W1, W2,
                                               eq, ek, ev, ep, e1, e2,
                                               bq, bk, bv, bp, b1, b2,
                                               Wqkvq, Wpq, W1q, W2q,
                                               x, g1, be1, hbuf);

    // QKV: [8192,3072] bf16, 8-wave gemm_bt (1536 blocks = 3 full rounds)
    gemm_bt<0><<<dim3(24, 64), 512, 0, stream>>>(hbuf, Wqkvq, 3072, 1024, nullptr, nullptr, nullptr, nullptr, qkvb);
    // attention (8-wave shared staging, supertile-paired)
    attn_kernel<<<dim3(4, 128), 512, 0, stream>>>(qkvb, attb);
    // proj + bias + residual(x fp32) -> x2b (bf16), 4-wave gemm_bt4
    gemm_bt4<3><<<dim3(8, 64), 256, 0, stream>>>(attb, Wpq, 1024, 1024, biasp, x, nullptr, nullptr, x2b);
    // LN2: x2b (bf16) -> hbuf
    ln_bf_kernel<<<2048, 256, 0, stream>>>(x2b, g2, be2, hbuf);
    // FFN1: relu(h2 W1^T + b1) -> f (bf16), 8-wave gemm_bt (2048 blocks = 4 full rounds)
    gemm_bt<2><<<dim3(32, 64), 512, 0, stream>>>(hbuf, W1q, 4096, 1024, bias1, nullptr, nullptr, nullptr, fbuf);
    // FFN2: f W2^T + b2 + x2b(bf16) -> out (fp32), 4-wave gemm_bt4
    gemm_bt4<4><<<dim3(8, 64), 256, 0, stream>>>(fbuf, W2q, 1024, 4096, bias2, nullptr, x2b, (float*)d_out, nullptr);
}

// Round 11
// 318.505 us; speedup vs baseline: 1.0356x; 1.0356x over previous
//
#include <hip/hip_runtime.h>
#include <hip/hip_bf16.h>
#include <math.h>

#define DEVI __device__ __forceinline__

typedef __attribute__((ext_vector_type(8))) short bf16x8;
typedef __attribute__((ext_vector_type(4))) float f32x4;

DEVI unsigned short f2bf(float f) {
    union { float f; unsigned u; } v; v.f = f;
    unsigned r = v.u + 0x7FFFu + ((v.u >> 16) & 1u);
    return (unsigned short)(r >> 16);
}

DEVI float bf2f(unsigned short u) {
    union { unsigned u; float f; } v; v.u = (unsigned)u << 16; return v.f;
}

DEVI unsigned cvtpk(float lo, float hi) {   // D = bf16(hi)<<16 | bf16(lo), RNE
    unsigned d;
    asm volatile("v_cvt_pk_bf16_f32 %0, %1, %2" : "=v"(d) : "v"(lo), "v"(hi));
    return d;
}

DEVI void gload16(const void* g, void* l) {
    __builtin_amdgcn_global_load_lds((const __attribute__((address_space(1))) void*)g,
                                     (__attribute__((address_space(3))) void*)l, 16, 0, 0);
}

#define WAITVM4() asm volatile("s_waitcnt vmcnt(4)" ::: "memory")
#define WAITVM0() asm volatile("s_waitcnt vmcnt(0)" ::: "memory")
#define WAITLG0() asm volatile("s_waitcnt lgkmcnt(0)" ::: "memory")
#define WAITLG8() asm volatile("s_waitcnt lgkmcnt(8)" ::: "memory")
#define BAR()     __builtin_amdgcn_s_barrier()
#define SB()      __builtin_amdgcn_sched_barrier(0)

// ---------------- fused pre-pass: 6 weight fake-quants + LN1, one dispatch ----------------
__global__ __launch_bounds__(256) void fused_pre_kernel(
    const float* __restrict__ Wq, const float* __restrict__ Wk, const float* __restrict__ Wv,
    const float* __restrict__ Wp, const float* __restrict__ W1, const float* __restrict__ W2,
    const float* __restrict__ eq, const float* __restrict__ ek, const float* __restrict__ ev,
    const float* __restrict__ ep, const float* __restrict__ e1, const float* __restrict__ e2,
    const float* __restrict__ bq, const float* __restrict__ bk, const float* __restrict__ bv,
    const float* __restrict__ bp, const float* __restrict__ b1, const float* __restrict__ b2,
    unsigned short* __restrict__ Wqkvq, unsigned short* __restrict__ Wpq,
    unsigned short* __restrict__ W1q, unsigned short* __restrict__ W2q,
    const float* __restrict__ x, const float* __restrict__ g1, const float* __restrict__ be1,
    unsigned short* __restrict__ hbuf)
{
    const int M1 = 1 << 20;
    if (blockIdx.x < 2048) {
        const int NCH = 3 * M1;
        const int STRIDE = 2048 * 256;
        for (int c = blockIdx.x * blockDim.x + threadIdx.x; c < NCH; c += STRIDE) {
            int elem = c * 4;
            const float *W, *e, *b; unsigned short* o; int lgK, local;
            if (elem < M1)            { W = Wq; e = eq; b = bq; o = Wqkvq;          lgK = 10; local = elem; }
            else if (elem < 2 * M1)   { W = Wk; e = ek; b = bk; o = Wqkvq + M1;     lgK = 10; local = elem - M1; }
            else if (elem < 3 * M1)   { W = Wv; e = ev; b = bv; o = Wqkvq + 2 * M1; lgK = 10; local = elem - 2 * M1; }
            else if (elem < 4 * M1)   { W = Wp; e = ep; b = bp; o = Wpq;            lgK = 10; local = elem - 3 * M1; }
            else if (elem < 8 * M1)   { W = W1; e = e1; b = b1; o = W1q;            lgK = 10; local = elem - 4 * M1; }
            else                      { W = W2; e = e2; b = b2; o = W2q;            lgK = 12; local = elem - 8 * M1; }
            int row = local >> lgK;
            float evv = e[row], bvv = b[row];
            float br = fmaxf(bvv, 0.f);
            float mn, mx;
            if (br > 0.f) { float p = exp2f(br - 1.f); mn = -p; mx = p - 1.f; }
            else          { mn = 0.f; mx = 0.f; }
            float si = exp2f(-evv), so = exp2f(evv);
            union { float4 v4; float a[4]; } v;
            v.v4 = *(const float4*)(W + local);
            union { unsigned short u[4]; unsigned long long ll; } ot;
            #pragma unroll
            for (int j = 0; j < 4; j++) {
                float qw = fminf(fmaxf(si * v.a[j], mn), mx);
                ot.u[j] = f2bf(so * rintf(qw));
            }
            *(unsigned long long*)(o + local) = ot.ll;
        }
    } else {
        int row = (blockIdx.x - 2048) * 4 + (threadIdx.x >> 6);
        int lane = threadIdx.x & 63;
        const float* xp = x + (size_t)row * 1024 + lane * 16;
        float a[16];
        #pragma unroll
        for (int j = 0; j < 4; j++) {
            float4 v = *(const float4*)(xp + j * 4);
            a[j * 4] = v.x; a[j * 4 + 1] = v.y; a[j * 4 + 2] = v.z; a[j * 4 + 3] = v.w;
        }
        float s = 0.f, s2 = 0.f;
        #pragma unroll
        for (int i = 0; i < 16; i++) { s += a[i]; s2 += a[i] * a[i]; }
        #pragma unroll
        for (int off = 1; off < 64; off <<= 1) { s += __shfl_xor(s, off); s2 += __shfl_xor(s2, off); }
        float mu = s * (1.0f / 1024.0f);
        float var = s2 * (1.0f / 1024.0f) - mu * mu;
        float rs = rsqrtf(var + 1e-5f);
        int c0 = lane * 16;
        float r[16];
        #pragma unroll
        for (int i = 0; i < 16; i++) r[i] = (a[i] - mu) * rs * g1[c0 + i] + be1[c0 + i];
        unsigned w[8];
        #pragma unroll
        for (int j = 0; j < 8; j++) w[j] = cvtpk(r[2 * j], r[2 * j + 1]);
        unsigned short* op = hbuf + (size_t)row * 1024 + c0;
        *(uint4*)(op)     = *(uint4*)&w[0];
        *(uint4*)(op + 8) = *(uint4*)&w[4];
    }
}

// ---------------- LayerNorm wave-per-row, bf16 in -> bf16 out (LN2) ----------------
__global__ __launch_bounds__(256) void ln_bf_kernel(
    const unsigned short* __restrict__ xb, const float* __restrict__ g, const float* __restrict__ be,
    unsigned short* __restrict__ out)
{
    int row = blockIdx.x * 4 + (threadIdx.x >> 6);
    int lane = threadIdx.x & 63;
    const unsigned short* xp = xb + (size_t)row * 1024 + lane * 16;
    float a[16];
    #pragma unroll
    for (int j = 0; j < 2; j++) {
        bf16x8 v = *(const bf16x8*)(xp + j * 8);
        #pragma unroll
        for (int i = 0; i < 8; i++) a[j * 8 + i] = bf2f(((unsigned short*)&v)[i]);
    }
    float s = 0.f, s2 = 0.f;
    #pragma unroll
    for (int i = 0; i < 16; i++) { s += a[i]; s2 += a[i] * a[i]; }
    #pragma unroll
    for (int off = 1; off < 64; off <<= 1) { s += __shfl_xor(s, off); s2 += __shfl_xor(s2, off); }
    float mu = s * (1.0f / 1024.0f);
    float var = s2 * (1.0f / 1024.0f) - mu * mu;
    float rs = rsqrtf(var + 1e-5f);
    int c0 = lane * 16;
    float r[16];
    #pragma unroll
    for (int i = 0; i < 16; i++) r[i] = (a[i] - mu) * rs * g[c0 + i] + be[c0 + i];
    unsigned w[8];
    #pragma unroll
    for (int j = 0; j < 8; j++) w[j] = cvtpk(r[2 * j], r[2 * j + 1]);
    unsigned short* op = out + (size_t)row * 1024 + c0;
    *(uint4*)(op)     = *(uint4*)&w[0];
    *(uint4*)(op + 8) = *(uint4*)&w[4];
}

// ---------------- GEMM 128x128, BK=64, 8 waves (64x32 wave-tile), counted-vmcnt 2-phase ----
// (r9 best-measured). EP 0: bf16. EP 3: bf16=acc+bias+res(f32). EP 4: f32=acc+bias+resb(bf16).
#define GSTAGE(buf, kt) do { \
    _Pragma("unroll") for (int q_ = 0; q_ < 2; q_++) { \
        int idx_ = q_ * 512 + tid; int row_ = idx_ >> 3; int gs_ = (idx_ & 7) ^ (row_ & 7); \
        gload16(A  + (size_t)(brow + row_) * K + (kt) * 64 + gs_ * 8, &As[buf][idx_ * 8]); \
        gload16(Bw + (size_t)(bcol + row_) * K + (kt) * 64 + gs_ * 8, &Bs[buf][idx_ * 8]); \
    } } while (0)

template<int EP>
__global__ __launch_bounds__(512, 2) void gemm_bt(
    const unsigned short* __restrict__ A, const unsigned short* __restrict__ Bw,
    int N, int K,
    const float* __restrict__ bias, const float* __restrict__ res,
    const unsigned short* __restrict__ resb,
    float* __restrict__ outf, unsigned short* __restrict__ outb)
{
    __shared__ __align__(16) unsigned short As[2][128 * 64];
    __shared__ __align__(16) unsigned short Bs[2][128 * 64];
    int tid = threadIdx.x, lane = tid & 63, wave = tid >> 6;
    int gx = gridDim.x;
    int nwg = gx * gridDim.y;
    int id = blockIdx.y * gx + blockIdx.x;
    int swz = (id & 7) * (nwg >> 3) + (id >> 3);
    int brow = (swz / gx) * 128, bcol = (swz % gx) * 128;
    int wr = wave >> 2, wc = wave & 3;       // 2 M-waves x 4 N-waves; wave tile 64x32
    int r = lane & 15, g4 = lane >> 4;
    f32x4 acc[4][2];
    #pragma unroll
    for (int i = 0; i < 4; i++)
        #pragma unroll
        for (int j = 0; j < 2; j++) acc[i][j] = (f32x4){0.f, 0.f, 0.f, 0.f};

    int nt = K >> 6;
    GSTAGE(0, 0);
    __syncthreads();
    int cur = 0;
    for (int t = 0; t < nt; ++t) {
        if (t + 1 < nt) { GSTAGE(cur ^ 1, t + 1); WAITVM4(); }
        else            { WAITVM0(); }
        __builtin_amdgcn_s_barrier();
        #pragma unroll
        for (int kk = 0; kk < 2; kk++) {
            bf16x8 af[4], bfr[2];
            #pragma unroll
            for (int mi = 0; mi < 4; mi++) {
                int rh = wr * 64 + mi * 16 + r;
                af[mi] = *(const bf16x8*)&As[cur][rh * 64 + (((kk * 4 + g4) ^ (rh & 7)) << 3)];
            }
            #pragma unroll
            for (int ni = 0; ni < 2; ni++) {
                int rh = wc * 32 + ni * 16 + r;
                bfr[ni] = *(const bf16x8*)&Bs[cur][rh * 64 + (((kk * 4 + g4) ^ (rh & 7)) << 3)];
            }
            #pragma unroll
            for (int mi = 0; mi < 4; mi++)
                #pragma unroll
                for (int ni = 0; ni < 2; ni++)
                    acc[mi][ni] = __builtin_amdgcn_mfma_f32_16x16x32_bf16(af[mi], bfr[ni], acc[mi][ni], 0, 0, 0);
        }
        __builtin_amdgcn_s_barrier();
        cur ^= 1;
    }

    #pragma unroll
    for (int mi = 0; mi < 4; mi++)
        #pragma unroll
        for (int ni = 0; ni < 2; ni++)
            #pragma unroll
            for (int i = 0; i < 4; i++) {
                int row = brow + wr * 64 + mi * 16 + g4 * 4 + i;
                int col = bcol + wc * 32 + ni * 16 + r;
                float v = acc[mi][ni][i];
                if (EP == 0) {
                    outb[(size_t)row * N + col] = f2bf(v);
                } else if (EP == 1) {
                    outf[(size_t)row * N + col] = v + bias[col] + res[(size_t)row * N + col];
                } else if (EP == 2) {
                    outb[(size_t)row * N + col] = f2bf(fmaxf(v + bias[col], 0.f));
                } else if (EP == 3) {
                    outb[(size_t)row * N + col] = f2bf(v + bias[col] + res[(size_t)row * N + col]);
                } else {
                    outf[(size_t)row * N + col] = v + bias[col] + bf2f(resb[(size_t)row * N + col]);
                }
            }
}

// ---------------- GEMM 256x256 8-phase (ledger-verified; clean r6-r9) — FFN1 ----------------
#define STAGE_A(b, h, kt) do { \
    _Pragma("unroll") \
    for (int ld = 0; ld < 2; ld++) { \
        int idx = ld * 512 + tid; int rw = idx >> 3; int gs = (idx & 7) ^ (rw & 7); \
        gload16(Aa + (size_t)(brow + (h) * 128 + rw) * K + (kt) * 64 + gs * 8, &As[b][h][idx * 8]); \
    } } while (0)

#define STAGE_B(b, h, kt) do { \
    _Pragma("unroll") \
    for (int ld = 0; ld < 2; ld++) { \
        int idx = ld * 512 + tid; int rw = idx >> 3; int gs = (idx & 7) ^ (rw & 7); \
        gload16(Bw + (size_t)(bcol + (h) * 128 + rw) * K + (kt) * 64 + gs * 8, &Bs[b][h][idx * 8]); \
    } } while (0)

#define RD_A(b, mh) do { \
    _Pragma("unroll") for (int mi = 0; mi < 4; mi++) \
    _Pragma("unroll") for (int kk = 0; kk < 2; kk++) { \
        int rh = (mh) * 64 + mi * 16 + r; \
        af[mi][kk] = *(const bf16x8*)&As[b][wr][rh * 64 + (((kk * 4 + g4) ^ (rh & 7)) << 3)]; \
    } } while (0)

#define RD_B2(b, nh) do { \
    _Pragma("unroll") for (int nj = 0; nj < 2; nj++) \
    _Pragma("unroll") for (int kk = 0; kk < 2; kk++) { \
        int rh = (wc & 1) * 64 + ((nh) * 2 + nj) * 16 + r; \
        bfr[(nh) * 2 + nj][kk] = *(const bf16x8*)&Bs[b][wc >> 1][rh * 64 + (((kk * 4 + g4) ^ (rh & 7)) << 3)]; \
    } } while (0)

#define QUAD(mh, nh) do { \
    __builtin_amdgcn_s_setprio(1); \
    _Pragma("unroll") for (int mi = 0; mi < 4; mi++) \
    _Pragma("unroll") for (int nj = 0; nj < 2; nj++) \
    _Pragma("unroll") for (int kk = 0; kk < 2; kk++) \
        acc[(mh) * 4 + mi][(nh) * 2 + nj] = __builtin_amdgcn_mfma_f32_16x16x32_bf16( \
            af[mi][kk], bfr[(nh) * 2 + nj][kk], acc[(mh) * 4 + mi][(nh) * 2 + nj], 0, 0, 0); \
    __builtin_amdgcn_s_setprio(0); \
    } while (0)

template<int EP>
__global__ __launch_bounds__(512, 2) void gemm256(
    const unsigned short* __restrict__ Aa, const unsigned short* __restrict__ Bw,
    int N, int K,
    const float* __restrict__ bias, const float* __restrict__ res,
    float* __restrict__ outf, unsigned short* __restrict__ outb)
{
    __shared__ __align__(16) unsigned short As[2][2][128 * 64];
    __shared__ __align__(16) unsigned short Bs[2][2][128 * 64];
    int tid = threadIdx.x, lane = tid & 63, wave = tid >> 6;
    int gx = gridDim.x;
    int nwg = gx * gridDim.y;
    int id = blockIdx.y * gx + blockIdx.x;
    int swz = (id & 7) * (nwg >> 3) + (id >> 3);
    int brow = (swz / gx) * 256, bcol = (swz % gx) * 256;
    int wr = wave >> 2, wc = wave & 3;
    int r = lane & 15, g4 = lane >> 4;
    int KT = K >> 6;

    f32x4 acc[8][4];
    #pragma unroll
    for (int i = 0; i < 8; i++)
        #pragma unroll
        for (int j = 0; j < 4; j++) acc[i][j] = (f32x4){0.f, 0.f, 0.f, 0.f};
    bf16x8 af[4][2], bfr[4][2];

    STAGE_A(0, 0, 0); STAGE_A(0, 1, 0); STAGE_B(0, 0, 0); STAGE_B(0, 1, 0);
    STAGE_B(1, 0, 1); STAGE_B(1, 1, 1);
    WAITVM4();
    BAR();

    for (int t = 0; t < KT; t += 2) {
        RD_A(0, 0); RD_B2(0, 0);
        STAGE_A(1, 0, t + 1);
        WAITLG8();
        BAR(); WAITLG0(); SB();
        QUAD(0, 0);
        BAR();
        RD_B2(0, 1);
        STAGE_A(1, 1, t + 1);
        BAR(); WAITLG0(); SB();
        QUAD(0, 1);
        BAR();
        RD_A(0, 1);
        if (t + 2 < KT) STAGE_B(0, 0, t + 2);
        BAR(); WAITLG0(); SB();
        QUAD(1, 1);
        BAR();
        if (t + 2 < KT) { STAGE_B(0, 1, t + 2); WAITVM4(); } else { WAITVM0(); }
        BAR(); WAITLG0(); SB();
        QUAD(1, 0);
        BAR();
        RD_A(1, 0); RD_B2(1, 0);
        if (t + 2 < KT) STAGE_A(0, 0, t + 2);
        WAITLG8();
        BAR(); WAITLG0(); SB();
        QUAD(0, 0);
        BAR();
        RD_B2(1, 1);
        if (t + 2 < KT) STAGE_A(0, 1, t + 2);
        BAR(); WAITLG0(); SB();
        QUAD(0, 1);
        BAR();
        RD_A(1, 1);
        if (t + 3 < KT) STAGE_B(1, 0, t + 3);
        BAR(); WAITLG0(); SB();
        QUAD(1, 1);
        BAR();
        if (t + 3 < KT) { STAGE_B(1, 1, t + 3); WAITVM4(); } else { WAITVM0(); }
        BAR(); WAITLG0(); SB();
        QUAD(1, 0);
        BAR();
    }

    #pragma unroll
    for (int m = 0; m < 8; m++)
        #pragma unroll
        for (int n = 0; n < 4; n++)
            #pragma unroll
            for (int j = 0; j < 4; j++) {
                int row = brow + wr * 128 + m * 16 + g4 * 4 + j;
                int col = bcol + wc * 64 + n * 16 + r;
                float v = acc[m][n][j];
                if (EP == 0) {
                    outb[(size_t)row * N + col] = f2bf(v);
                } else if (EP == 1) {
                    outf[(size_t)row * N + col] = v + bias[col] + res[(size_t)row * N + col];
                } else {
                    outb[(size_t)row * N + col] = f2bf(fmaxf(v + bias[col], 0.f));
                }
            }
}

// ---------------- Flash attention: 8 waves, 2 q-tiles share staged K/V ----------------
__global__ __launch_bounds__(512, 4) void attn_kernel(
    const unsigned short* __restrict__ qkv, unsigned short* __restrict__ att)
{
    __shared__ __align__(16) unsigned short Ks[2][64 * 64];
    __shared__ __align__(16) unsigned short Vt[2][64 * 66];
    __shared__ __align__(16) unsigned short Ps[2][64 * 64];
    int tid = threadIdx.x, lane = tid & 63, w = tid >> 6;
    int half = w >> 2;
    int pi = blockIdx.x;                       // 0..3
    int bh = blockIdx.y, bb = bh >> 4, hh = bh & 15;
    int r = lane & 15, g4 = lane >> 4;
    const unsigned short* base = qkv + (size_t)bb * 1024 * 3072;
    const float SCL = 0.03125f * 1.4426950408889634f;
    int vd = tid & 63, vsb = tid >> 6;
    int prow = (w & 3) * 16 + r;
    int pswz = (r & 7) << 3;

    for (int sidx = 0; sidx < 2; sidx++) {
        int s = sidx ? (7 - pi) : pi;
        int qt = 2 * s + half;
        int qtmax = 2 * s + 1;
        int qrow = qt * 64 + prow;

        bf16x8 qf[2];
        #pragma unroll
        for (int kk = 0; kk < 2; kk++)
            qf[kk] = *(const bf16x8*)&base[(size_t)qrow * 3072 + hh * 64 + kk * 32 + g4 * 8];

        f32x4 oacc[4];
        #pragma unroll
        for (int i = 0; i < 4; i++) oacc[i] = (f32x4){0.f, 0.f, 0.f, 0.f};
        float m_i = -INFINITY, l_i = 0.f;

        unsigned short vtmp[8];
        {
            int row = tid >> 3, slot = tid & 7;
            int gs = slot ^ (row & 7);
            gload16(base + (size_t)row * 3072 + 1024 + hh * 64 + gs * 8, &Ks[0][tid * 8]);
            #pragma unroll
            for (int i2 = 0; i2 < 8; i2++)
                vtmp[i2] = base[(size_t)(vsb * 8 + i2) * 3072 + 2048 + hh * 64 + vd];
            union { unsigned short u[8]; bf16x8 v; } w0;
            #pragma unroll
            for (int i2 = 0; i2 < 8; i2++) w0.u[i2] = vtmp[i2];
            *(bf16x8*)&Vt[0][vd * 66 + (vsb ^ (vd & 7)) * 8] = w0.v;
        }
        __syncthreads();

        for (int ki = 0; ki <= qtmax; ki++) {
            int cur = ki & 1;
            bool pre = (ki < qtmax);
            bool act = (ki <= qt);
            if (pre) {
                int k1 = (ki + 1) * 64;
                int row = tid >> 3, slot = tid & 7;
                int gs = slot ^ (row & 7);
                gload16(base + (size_t)(k1 + row) * 3072 + 1024 + hh * 64 + gs * 8, &Ks[cur ^ 1][tid * 8]);
                #pragma unroll
                for (int i2 = 0; i2 < 8; i2++)
                    vtmp[i2] = base[(size_t)(k1 + vsb * 8 + i2) * 3072 + 2048 + hh * 64 + vd];
            }

            if (act) {
                int k0 = ki * 64;
                f32x4 sacc[4];
                #pragma unroll
                for (int c4 = 0; c4 < 4; c4++) sacc[c4] = (f32x4){0.f, 0.f, 0.f, 0.f};
                #pragma unroll
                for (int c4 = 0; c4 < 4; c4++) {
                    int krow = c4 * 16 + r;
                    #pragma unroll
                    for (int kk = 0; kk < 2; kk++) {
                        int slot = (g4 + kk * 4) ^ (krow & 7);
                        bf16x8 kf = *(const bf16x8*)&Ks[cur][krow * 64 + slot * 8];
                        sacc[c4] = __builtin_amdgcn_mfma_f32_16x16x32_bf16(kf, qf[kk], sacc[c4], 0, 0, 0);
                    }
                }
                bool diag = (ki == qt);
                float sv[4][4];
                float smax = -INFINITY;
                #pragma unroll
                for (int c4 = 0; c4 < 4; c4++)
                    #pragma unroll
                    for (int i = 0; i < 4; i++) {
                        float sa = sacc[c4][i];
                        if (diag && (k0 + c4 * 16 + g4 * 4 + i) > qrow) sa = -INFINITY;
                        sv[c4][i] = sa;
                        smax = fmaxf(smax, sa);
                    }
                smax = fmaxf(smax, __shfl_xor(smax, 16));
                smax = fmaxf(smax, __shfl_xor(smax, 32));
                if (!__all((smax - m_i) * SCL <= 8.f)) {
                    float mn = fmaxf(m_i, smax);
                    float fs = exp2f((m_i - mn) * SCL);
                    m_i = mn;
                    l_i *= fs;
                    #pragma unroll
                    for (int n4 = 0; n4 < 4; n4++)
                        #pragma unroll
                        for (int i = 0; i < 4; i++) oacc[n4][i] *= fs;
                }
                float nb = -m_i * SCL;
                float rsum = 0.f;
                float pv[4][4];
                #pragma unroll
                for (int c4 = 0; c4 < 4; c4++)
                    #pragma unroll
                    for (int i = 0; i < 4; i++) {
                        float p = exp2f(fmaf(sv[c4][i], SCL, nb));
                        pv[c4][i] = p;
                        rsum += p;
                    }
                rsum += __shfl_xor(rsum, 16);
                rsum += __shfl_xor(rsum, 32);
                l_i += rsum;
                #pragma unroll
                for (int c4 = 0; c4 < 4; c4++) {
                    unsigned long long ll = (unsigned long long)cvtpk(pv[c4][0], pv[c4][1])
                                          | ((unsigned long long)cvtpk(pv[c4][2], pv[c4][3]) << 32);
                    *(unsigned long long*)&Ps[half][(prow * 64 + c4 * 16 + g4 * 4) ^ pswz] = ll;
                }
                WAITLG0();
            }
            if (pre) {
                union { unsigned short u[8]; bf16x8 v; } w0;
                #pragma unroll
                for (int i2 = 0; i2 < 8; i2++) w0.u[i2] = vtmp[i2];
                *(bf16x8*)&Vt[cur ^ 1][vd * 66 + (vsb ^ (vd & 7)) * 8] = w0.v;
            }
            if (act) {
                bf16x8 pa[2];
                #pragma unroll
                for (int kk = 0; kk < 2; kk++)
                    pa[kk] = *(const bf16x8*)&Ps[half][(prow * 64 + kk * 32 + g4 * 8) ^ pswz];
                #pragma unroll
                for (int n4 = 0; n4 < 4; n4++) {
                    int d = n4 * 16 + r;
                    #pragma unroll
                    for (int kk = 0; kk < 2; kk++) {
                        bf16x8 vf = *(const bf16x8*)&Vt[cur][d * 66 + (((kk * 4 + g4) ^ (d & 7)) << 3)];
                        oacc[n4] = __builtin_amdgcn_mfma_f32_16x16x32_bf16(vf, pa[kk], oacc[n4], 0, 0, 0);
                    }
                }
            }
            __syncthreads();
        }

        float inv = 1.f / l_i;
        #pragma unroll
        for (int n4 = 0; n4 < 4; n4++) {
            unsigned long long ll = (unsigned long long)cvtpk(oacc[n4][0] * inv, oacc[n4][1] * inv)
                                  | ((unsigned long long)cvtpk(oacc[n4][2] * inv, oacc[n4][3] * inv) << 32);
            size_t oidx = ((size_t)(bb * 1024 + qrow)) * 1024 + hh * 64 + n4 * 16 + g4 * 4;
            *(unsigned long long*)&att[oidx] = ll;
        }
    }
}

// ---------------- host (r9 best-measured configuration) ----------------
extern "C" void kernel_launch(void* const* d_in, const int* in_sizes, int n_in,
                              void* d_out, int out_size, void* d_ws, size_t ws_size,
                              hipStream_t stream)
{
    const float* x     = (const float*)d_in[0];
    const float* Wq    = (const float*)d_in[1];
    const float* Wk    = (const float*)d_in[2];
    const float* Wv    = (const float*)d_in[3];
    const float* eq    = (const float*)d_in[4];
    const float* bq    = (const float*)d_in[5];
    const float* ek    = (const float*)d_in[6];
    const float* bk    = (const float*)d_in[7];
    const float* ev    = (const float*)d_in[8];
    const float* bv    = (const float*)d_in[9];
    const float* Wp    = (const float*)d_in[10];
    const float* ep    = (const float*)d_in[11];
    const float* bp    = (const float*)d_in[12];
    const float* biasp = (const float*)d_in[13];
    const float* W1    = (const float*)d_in[14];
    const float* e1    = (const float*)d_in[15];
    const float* b1    = (const float*)d_in[16];
    const float* bias1 = (const float*)d_in[17];
    const float* W2    = (const float*)d_in[18];
    const float* e2    = (const float*)d_in[19];
    const float* b2    = (const float*)d_in[20];
    const float* bias2 = (const float*)d_in[21];
    const float* g1    = (const float*)d_in[22];
    const float* be1   = (const float*)d_in[23];
    const float* g2    = (const float*)d_in[24];
    const float* be2   = (const float*)d_in[25];

    const size_t MB = 1ull << 20;
    char* ws = (char*)d_ws;
    unsigned short* Wqkvq = (unsigned short*)(ws);            //  6 MB
    unsigned short* Wpq   = (unsigned short*)(ws + 6 * MB);   //  2 MB
    unsigned short* W1q   = (unsigned short*)(ws + 8 * MB);   //  8 MB
    unsigned short* W2q   = (unsigned short*)(ws + 16 * MB);  //  8 MB
    unsigned short* hbuf  = (unsigned short*)(ws + 24 * MB);  // 16 MB
    unsigned short* qkvb  = (unsigned short*)(ws + 40 * MB);  // 48 MB; later f (64 MB)
    unsigned short* fbuf  = qkvb;
    unsigned short* attb  = (unsigned short*)(ws + 88 * MB);  // 16 MB
    unsigned short* x2b   = (unsigned short*)(ws + 104 * MB); // 16 MB (bf16 residual)

    fused_pre_kernel<<<4096, 256, 0, stream>>>(Wq, Wk, Wv, Wp, W1, W2,
                                               eq, ek, ev, ep, e1, e2,
                                               bq, bk, bv, bp, b1, b2,
                                               Wqkvq, Wpq, W1q, W2q,
                                               x, g1, be1, hbuf);

    // QKV: [8192,3072] bf16, 8-wave gemm_bt (1536 blocks = 3 full rounds)
    gemm_bt<0><<<dim3(24, 64), 512, 0, stream>>>(hbuf, Wqkvq, 3072, 1024, nullptr, nullptr, nullptr, nullptr, qkvb);
    // attention (8-wave shared staging, supertile-paired)
    attn_kernel<<<dim3(4, 128), 512, 0, stream>>>(qkvb, attb);
    // proj + bias + residual(x fp32) -> x2b (bf16), 8-wave gemm_bt
    gemm_bt<3><<<dim3(8, 64), 512, 0, stream>>>(attb, Wpq, 1024, 1024, biasp, x, nullptr, nullptr, x2b);
    // LN2: x2b (bf16) -> hbuf
    ln_bf_kernel<<<2048, 256, 0, stream>>>(x2b, g2, be2, hbuf);
    // FFN1: relu(h2 W1^T + b1) -> f (bf16), 256^2 8-phase gemm256
    gemm256<2><<<dim3(16, 32), 512, 0, stream>>>(hbuf, W1q, 4096, 1024, bias1, nullptr, nullptr, fbuf);
    // FFN2: f W2^T + b2 + x2b(bf16) -> out (fp32), 8-wave gemm_bt
    gemm_bt<4><<<dim3(8, 64), 512, 0, stream>>>(fbuf, W2q, 1024, 4096, bias2, nullptr, x2b, (float*)d_out, nullptr);
}